// Round 8
// baseline (564.204 us; speedup 1.0000x reference)
//
#include <hip/hip_runtime.h>
#include <math.h>

#define N_NODES 50000
#define N_EDGES 800000
#define ETOT    (N_EDGES + N_NODES)   // 850000, with self loops

typedef short bf16x8 __attribute__((ext_vector_type(8)));
typedef float f32x4  __attribute__((ext_vector_type(4)));

__device__ __forceinline__ float b2f(unsigned int u16) {   // low 16 bits hold bf16
    return __uint_as_float(u16 << 16);
}
__device__ __forceinline__ unsigned short f2b(float f) {   // RNE
    unsigned int u = __float_as_uint(f);
    u += 0x7fffu + ((u >> 16) & 1u);
    return (unsigned short)(u >> 16);
}
// unpack uint4 (8 bf16) -> 8 floats
__device__ __forceinline__ void unpack8(uint4 v, float* f) {
    f[0] = __uint_as_float(v.x << 16); f[1] = __uint_as_float(v.x & 0xffff0000u);
    f[2] = __uint_as_float(v.y << 16); f[3] = __uint_as_float(v.y & 0xffff0000u);
    f[4] = __uint_as_float(v.z << 16); f[5] = __uint_as_float(v.z & 0xffff0000u);
    f[6] = __uint_as_float(v.w << 16); f[7] = __uint_as_float(v.w & 0xffff0000u);
}

// ---------------------------------------------------------------------------
// Edge-index dtype detection (reference int64 vs harness int32).
// ---------------------------------------------------------------------------
__global__ void k_detect(const int* __restrict__ idx, int* __restrict__ flag) {
    int i = blockIdx.x * blockDim.x + threadIdx.x;   // 8192 threads
    int v = idx[2 * i + 1];
    unsigned long long any = __ballot(v != 0);
    if ((threadIdx.x & 63) == 0 && any) atomicOr(flag, 1);   // 1 => int32 data
}

__device__ __forceinline__ int edge_src(const int* idx, int e, int is32) {
    return is32 ? idx[e] : idx[2 * e];
}
__device__ __forceinline__ int edge_dst(const int* idx, int e, int is32) {
    return is32 ? idx[N_EDGES + e] : idx[2 * (N_EDGES + e)];
}

// ---------------------------------------------------------------------------
// CSR build: degree -> 3-kernel scan -> scatter
// ---------------------------------------------------------------------------
__global__ void k_degree(const int* __restrict__ idx, const int* __restrict__ flag,
                         int* __restrict__ deg) {
    int e = blockIdx.x * blockDim.x + threadIdx.x;
    if (e >= ETOT) return;
    int is32 = *flag;
    int d = (e < N_EDGES) ? edge_dst(idx, e, is32) : (e - N_EDGES);
    atomicAdd(&deg[d], 1);
}

__global__ __launch_bounds__(256) void k_scan1(const int* __restrict__ deg,
                                               int* __restrict__ rowptr,
                                               int* __restrict__ bsum) {
    __shared__ int sd[256];
    int t = threadIdx.x;
    int i = blockIdx.x * 256 + t;
    int v = (i < N_NODES) ? deg[i] : 0;
    sd[t] = v;
    __syncthreads();
#pragma unroll
    for (int off = 1; off < 256; off <<= 1) {
        int a = (t >= off) ? sd[t - off] : 0;
        __syncthreads();
        sd[t] += a;
        __syncthreads();
    }
    if (i < N_NODES) rowptr[i] = sd[t] - v;    // block-local exclusive
    if (t == 255) bsum[blockIdx.x] = sd[255];
}

__global__ __launch_bounds__(256) void k_scan2(int* __restrict__ bsum,
                                               int* __restrict__ boff,
                                               int* __restrict__ rowptr,
                                               int nb) {
    __shared__ int sd[256];
    int t = threadIdx.x;
    int v = (t < nb) ? bsum[t] : 0;
    sd[t] = v;
    __syncthreads();
#pragma unroll
    for (int off = 1; off < 256; off <<= 1) {
        int a = (t >= off) ? sd[t - off] : 0;
        __syncthreads();
        sd[t] += a;
        __syncthreads();
    }
    boff[t] = sd[t] - v;                        // exclusive
    if (t == 255) rowptr[N_NODES] = sd[255];
}

__global__ __launch_bounds__(256) void k_scan3(int* __restrict__ rowptr,
                                               const int* __restrict__ boff,
                                               int* __restrict__ cursor) {
    int i = blockIdx.x * 256 + threadIdx.x;
    if (i >= N_NODES) return;
    int r = rowptr[i] + boff[blockIdx.x];
    rowptr[i] = r;
    cursor[i] = r;
}

__global__ void k_scatter(const int* __restrict__ idx, const int* __restrict__ flag,
                          int* __restrict__ cursor, int* __restrict__ col) {
    int e = blockIdx.x * blockDim.x + threadIdx.x;
    if (e >= ETOT) return;
    int is32 = *flag;
    int s, d;
    if (e < N_EDGES) { s = edge_src(idx, e, is32); d = edge_dst(idx, e, is32); }
    else             { s = d = e - N_EDGES; }
    int pos = atomicAdd(&cursor[d], 1);
    col[pos] = s;
}

// ---------------------------------------------------------------------------
// fp32 -> bf16 cast for weights (x consumed fp32 by k_gemm1 directly)
// ---------------------------------------------------------------------------
__global__ void k_cast_w(const float* __restrict__ w1, const float* __restrict__ w2,
                         const float* __restrict__ w3,
                         unsigned short* __restrict__ o1, unsigned short* __restrict__ o2,
                         unsigned short* __restrict__ o3) {
    int i = blockIdx.x * blockDim.x + threadIdx.x;
    if (i < 512 * 128 / 4) {
        float4 v = ((const float4*)w1)[i];
        ushort2* o = (ushort2*)(o1 + i * 4);
        o[0] = make_ushort2(f2b(v.x), f2b(v.y));
        o[1] = make_ushort2(f2b(v.z), f2b(v.w));
    }
    if (i < 64 * 512 / 4) {
        float4 v = ((const float4*)w2)[i];
        ushort2* o = (ushort2*)(o2 + i * 4);
        o[0] = make_ushort2(f2b(v.x), f2b(v.y));
        o[1] = make_ushort2(f2b(v.z), f2b(v.w));
    }
    if (i < 64 * 64 / 4) {
        float4 v = ((const float4*)w3)[i];
        ushort2* o = (ushort2*)(o3 + i * 4);
        o[0] = make_ushort2(f2b(v.x), f2b(v.y));
        o[1] = make_ushort2(f2b(v.z), f2b(v.w));
    }
}

// ---------------------------------------------------------------------------
// Layer-1 GEMM: h1[M,512] = x[M,128] @ W1[512,128]^T, x fp32 -> bf16 staged.
// 64-row tile, FULL K=128 of A resident in LDS (staged once per block);
// inner loop over 8 heads re-stages only B (16 KB, L2-hit) -- cuts the 8x
// A re-fetch of the old 8-col-block grid. Same per-output K order as before
// -> h1 bitwise identical. Epilogue computes attention coefficients per head.
// ---------------------------------------------------------------------------
__global__ __launch_bounds__(256) void k_gemm1(const float* __restrict__ Af,
                                               const unsigned short* __restrict__ W,
                                               unsigned short* __restrict__ C,
                                               const float* __restrict__ a_src,
                                               const float* __restrict__ a_dst,
                                               float* __restrict__ asb,
                                               float* __restrict__ adb,
                                               int M) {
    __shared__ unsigned short As[64 * 136];  // 64 rows x 128 K, stride 136
    __shared__ unsigned short Bs[64 * 136];
    __shared__ float red_s[4][64];
    __shared__ float red_d[4][64];
    int t = threadIdx.x;
    int w = t >> 6, l = t & 63;
    int quad = l >> 4, lm = l & 15;
    int m0 = blockIdx.x * 64;
    int lr = t >> 2;            // staging row 0..63
    int lcb = (t & 3) * 8;      // staging col base 0/8/16/24

    // Stage A (fp32 -> bf16), all 128 K columns
#pragma unroll
    for (int seg = 0; seg < 4; ++seg) {
        int colf = lcb + seg * 32;
        int m = m0 + lr;
        float4 a0 = {0.f,0.f,0.f,0.f}, a1 = {0.f,0.f,0.f,0.f};
        if (m < M) {
            const float4* ap = (const float4*)(Af + (size_t)m * 128 + colf);
            a0 = ap[0]; a1 = ap[1];
        }
        unsigned int u0 = (unsigned int)f2b(a0.x) | ((unsigned int)f2b(a0.y) << 16);
        unsigned int u1 = (unsigned int)f2b(a0.z) | ((unsigned int)f2b(a0.w) << 16);
        unsigned int u2 = (unsigned int)f2b(a1.x) | ((unsigned int)f2b(a1.y) << 16);
        unsigned int u3 = (unsigned int)f2b(a1.z) | ((unsigned int)f2b(a1.w) << 16);
        *(uint4*)&As[lr * 136 + colf] = make_uint4(u0, u1, u2, u3);
    }
    __syncthreads();

    for (int hd = 0; hd < 8; ++hd) {
        // Stage B: rows [hd*64, hd*64+64) of W1 (bf16), all 128 K
#pragma unroll
        for (int seg = 0; seg < 4; ++seg) {
            int colf = lcb + seg * 32;
            uint4 bv = *(const uint4*)(W + (size_t)(hd * 64 + lr) * 128 + colf);
            *(uint4*)&Bs[lr * 136 + colf] = bv;
        }
        __syncthreads();

        f32x4 acc[4];
#pragma unroll
        for (int r = 0; r < 4; ++r) acc[r] = (f32x4){0.f, 0.f, 0.f, 0.f};

#pragma unroll
        for (int k0 = 0; k0 < 4; ++k0) {
            int koff = k0 * 32 + quad * 8;
            bf16x8 bfrag = *(const bf16x8*)&Bs[(w * 16 + lm) * 136 + koff];
#pragma unroll
            for (int r = 0; r < 4; ++r) {
                bf16x8 afrag = *(const bf16x8*)&As[(r * 16 + lm) * 136 + koff];
                acc[r] = __builtin_amdgcn_mfma_f32_16x16x32_bf16(afrag, bfrag, acc[r], 0, 0, 0);
            }
        }

        // C store (bf16), cols hd*64 + w*16 + lm
#pragma unroll
        for (int r = 0; r < 4; ++r)
#pragma unroll
            for (int g = 0; g < 4; ++g) {
                int m = m0 + r * 16 + quad * 4 + g;
                if (m < M) C[(size_t)m * 512 + hd * 64 + w * 16 + lm] = f2b(acc[r][g]);
            }

        // Attention-coefficient epilogue for this head
        float as = a_src[hd * 64 + w * 16 + lm];
        float ad = a_dst[hd * 64 + w * 16 + lm];
#pragma unroll
        for (int r = 0; r < 4; ++r) {
#pragma unroll
            for (int g = 0; g < 4; ++g) {
                float vs = acc[r][g] * as;
                float vd = acc[r][g] * ad;
#pragma unroll
                for (int off = 1; off < 16; off <<= 1) {
                    vs += __shfl_xor(vs, off);
                    vd += __shfl_xor(vd, off);
                }
                if (lm == 0) {
                    red_s[w][r * 16 + quad * 4 + g] = vs;
                    red_d[w][r * 16 + quad * 4 + g] = vd;
                }
            }
        }
        __syncthreads();
        if (t < 64) {
            float vs = red_s[0][t] + red_s[1][t] + red_s[2][t] + red_s[3][t];
            float vd = red_d[0][t] + red_d[1][t] + red_d[2][t] + red_d[3][t];
            int m = m0 + t;
            if (m < M) {
                asb[(size_t)m * 8 + hd] = vs;
                adb[(size_t)m * 8 + hd] = vd;
            }
        }
        // next iteration's B-stage / red-write ordering handled by the
        // __syncthreads() at the top of the next hd's B-stage
        __syncthreads();
    }
}

// ---------------------------------------------------------------------------
// Layer-2 GEMM: h2[M,64] = x2[M,512] @ W2[64,512]^T (bf16 MFMA, 64x64 tile).
// Epilogue computes layer-2 attention coefficients (single head).
// ---------------------------------------------------------------------------
__global__ __launch_bounds__(256) void k_gemm(const unsigned short* __restrict__ A,
                                              const unsigned short* __restrict__ W,
                                              unsigned short* __restrict__ C,
                                              const float* __restrict__ a_src,
                                              const float* __restrict__ a_dst,
                                              float* __restrict__ asb,
                                              float* __restrict__ adb,
                                              int M, int K) {
    __shared__ unsigned short As[64 * 40];
    __shared__ unsigned short Bs[64 * 40];
    __shared__ float red_s[4][64];
    __shared__ float red_d[4][64];
    int t = threadIdx.x;
    int w = t >> 6, l = t & 63;
    int quad = l >> 4, lm = l & 15;
    int m0 = blockIdx.y * 64;
    int lr = t >> 2;
    int lc = (t & 3) * 8;

    f32x4 acc[4];
#pragma unroll
    for (int r = 0; r < 4; ++r) acc[r] = (f32x4){0.f, 0.f, 0.f, 0.f};

    for (int k0 = 0; k0 < K; k0 += 32) {
        int m = m0 + lr;
        uint4 av = make_uint4(0, 0, 0, 0);
        if (m < M) av = *(const uint4*)(A + (size_t)m * K + k0 + lc);
        *(uint4*)&As[lr * 40 + lc] = av;
        uint4 bv = *(const uint4*)(W + (size_t)lr * K + k0 + lc);
        *(uint4*)&Bs[lr * 40 + lc] = bv;
        __syncthreads();

        bf16x8 bfrag = *(const bf16x8*)&Bs[(w * 16 + lm) * 40 + quad * 8];
#pragma unroll
        for (int r = 0; r < 4; ++r) {
            bf16x8 afrag = *(const bf16x8*)&As[(r * 16 + lm) * 40 + quad * 8];
            acc[r] = __builtin_amdgcn_mfma_f32_16x16x32_bf16(afrag, bfrag, acc[r], 0, 0, 0);
        }
        __syncthreads();
    }

#pragma unroll
    for (int r = 0; r < 4; ++r)
#pragma unroll
        for (int g = 0; g < 4; ++g) {
            int m = m0 + r * 16 + quad * 4 + g;
            if (m < M) C[(size_t)m * 64 + w * 16 + lm] = f2b(acc[r][g]);
        }

    float as = a_src[w * 16 + lm];
    float ad = a_dst[w * 16 + lm];
#pragma unroll
    for (int r = 0; r < 4; ++r) {
#pragma unroll
        for (int g = 0; g < 4; ++g) {
            float vs = acc[r][g] * as;
            float vd = acc[r][g] * ad;
#pragma unroll
            for (int off = 1; off < 16; off <<= 1) {
                vs += __shfl_xor(vs, off);
                vd += __shfl_xor(vd, off);
            }
            if (lm == 0) {
                red_s[w][r * 16 + quad * 4 + g] = vs;
                red_d[w][r * 16 + quad * 4 + g] = vd;
            }
        }
    }
    __syncthreads();
    if (t < 64) {
        float vs = red_s[0][t] + red_s[1][t] + red_s[2][t] + red_s[3][t];
        float vd = red_d[0][t] + red_d[1][t] + red_d[2][t] + red_d[3][t];
        int m = m0 + t;
        if (m < M) {
            asb[m] = vs;
            adb[m] = vd;
        }
    }
}

// ---------------------------------------------------------------------------
// Fused segment-softmax + aggregation, H=8, C=64 (layer 1), bf16 h.
// Single pass, no max subtraction (|e| <= ~2 analytically). Unrolled x4.
// ---------------------------------------------------------------------------
__global__ __launch_bounds__(256) void k_agg8(const unsigned short* __restrict__ h, // [N,512]
                                              const float* __restrict__ asrc,       // [N,8]
                                              const float* __restrict__ adst,       // [N,8]
                                              const int* __restrict__ rowptr,
                                              const int* __restrict__ col,
                                              const float* __restrict__ bias,       // [512]
                                              unsigned short* __restrict__ out) {   // [N,512]
    int n = blockIdx.x * 4 + (threadIdx.x >> 6);
    if (n >= N_NODES) return;
    int l = threadIdx.x & 63;
    int j = l >> 3;
    int start = rowptr[n], end = rowptr[n + 1];
    float adn = adst[n * 8 + j];

    float ssum = 0.f;
    float o[8] = {0.f, 0.f, 0.f, 0.f, 0.f, 0.f, 0.f, 0.f};
    int k = start;
    for (; k + 4 <= end; k += 4) {
        int s0 = col[k], s1 = col[k + 1], s2 = col[k + 2], s3 = col[k + 3];
        float t0 = asrc[s0 * 8 + j], t1 = asrc[s1 * 8 + j];
        float t2 = asrc[s2 * 8 + j], t3 = asrc[s3 * 8 + j];
        uint4 hv0 = *(const uint4*)(h + (size_t)s0 * 512 + l * 8);
        uint4 hv1 = *(const uint4*)(h + (size_t)s1 * 512 + l * 8);
        uint4 hv2 = *(const uint4*)(h + (size_t)s2 * 512 + l * 8);
        uint4 hv3 = *(const uint4*)(h + (size_t)s3 * 512 + l * 8);
        float f[8];
        float e0 = t0 + adn; e0 = (e0 > 0.f) ? e0 : 0.2f * e0;
        float ex0 = __expf(e0); ssum += ex0;
        unpack8(hv0, f);
#pragma unroll
        for (int i = 0; i < 8; ++i) o[i] += ex0 * f[i];
        float e1 = t1 + adn; e1 = (e1 > 0.f) ? e1 : 0.2f * e1;
        float ex1 = __expf(e1); ssum += ex1;
        unpack8(hv1, f);
#pragma unroll
        for (int i = 0; i < 8; ++i) o[i] += ex1 * f[i];
        float e2 = t2 + adn; e2 = (e2 > 0.f) ? e2 : 0.2f * e2;
        float ex2 = __expf(e2); ssum += ex2;
        unpack8(hv2, f);
#pragma unroll
        for (int i = 0; i < 8; ++i) o[i] += ex2 * f[i];
        float e3 = t3 + adn; e3 = (e3 > 0.f) ? e3 : 0.2f * e3;
        float ex3 = __expf(e3); ssum += ex3;
        unpack8(hv3, f);
#pragma unroll
        for (int i = 0; i < 8; ++i) o[i] += ex3 * f[i];
    }
    for (; k < end; ++k) {
        int s = col[k];
        float e = asrc[s * 8 + j] + adn;
        e = (e > 0.f) ? e : 0.2f * e;
        float ex = __expf(e);
        ssum += ex;
        uint4 hv = *(const uint4*)(h + (size_t)s * 512 + l * 8);
        float f[8];
        unpack8(hv, f);
#pragma unroll
        for (int i = 0; i < 8; ++i) o[i] += ex * f[i];
    }
    float inv = 1.f / (ssum + 1e-16f);
    unsigned int p[4];
#pragma unroll
    for (int i = 0; i < 4; ++i) {
        float v0 = o[2 * i] * inv + bias[l * 8 + 2 * i];
        float v1 = o[2 * i + 1] * inv + bias[l * 8 + 2 * i + 1];
        v0 = (v0 > 0.f) ? v0 : expm1f(v0);
        v1 = (v1 > 0.f) ? v1 : expm1f(v1);
        p[i] = (unsigned int)f2b(v0) | ((unsigned int)f2b(v1) << 16);
    }
    *(uint4*)(out + (size_t)n * 512 + l * 8) = make_uint4(p[0], p[1], p[2], p[3]);
}

// ---------------------------------------------------------------------------
// Layer-2 aggregation + FUSED layer-3 linear (64x64 matvec) + layer-3 attn
// coefficients. One wave per dst node; lane = channel. The aggregated,
// biased, ELU'd value v (= x3[n][l], fp32 -- no bf16 roundtrip) is pushed
// through W3 via shuffle-broadcast matvec using LDS-resident W3, producing
// h3[n][l]; then a3 coefficients by wave reduction. Eliminates the gemm3
// dispatch and the x3 intermediate entirely.
// NOTE: writes go to as2/ad2 (NOT the asrc/adst being gathered -- race-free).
// Grid is exactly N_NODES/4 blocks; no early returns (barrier-safe).
// ---------------------------------------------------------------------------
__global__ __launch_bounds__(256) void k_agg1_mid(const unsigned short* __restrict__ h, // [N,64]
                                                  const float* __restrict__ asrc,       // [N]
                                                  const float* __restrict__ adst,       // [N]
                                                  const int* __restrict__ rowptr,
                                                  const int* __restrict__ col,
                                                  const float* __restrict__ bias,       // [64] b2
                                                  const unsigned short* __restrict__ W3b,// [64,64]
                                                  const float* __restrict__ a3s,        // [64]
                                                  const float* __restrict__ a3d,        // [64]
                                                  unsigned short* __restrict__ h3,      // [N,64]
                                                  float* __restrict__ as2,              // [N]
                                                  float* __restrict__ ad2) {            // [N]
    __shared__ unsigned short sW3[64 * 68];   // stride 68: 2-way bank alias (free)
    int t = threadIdx.x;
    // stage W3 (8 KB): 256 threads x 16 shorts
    {
        int r0 = t >> 2, c0 = (t & 3) * 16;
        *(uint4*)&sW3[r0 * 68 + c0]     = *(const uint4*)(W3b + r0 * 64 + c0);
        *(uint4*)&sW3[r0 * 68 + c0 + 8] = *(const uint4*)(W3b + r0 * 64 + c0 + 8);
    }
    __syncthreads();

    int n = blockIdx.x * 4 + (t >> 6);
    int l = t & 63;
    int start = rowptr[n], end = rowptr[n + 1];
    float adn = adst[n];

    float ssum = 0.f, o = 0.f;
    int k = start;
    for (; k + 4 <= end; k += 4) {
        int s0 = col[k], s1 = col[k + 1], s2 = col[k + 2], s3 = col[k + 3];
        float t0 = asrc[s0], t1 = asrc[s1], t2 = asrc[s2], t3 = asrc[s3];
        unsigned short q0 = h[(size_t)s0 * 64 + l];
        unsigned short q1 = h[(size_t)s1 * 64 + l];
        unsigned short q2 = h[(size_t)s2 * 64 + l];
        unsigned short q3 = h[(size_t)s3 * 64 + l];
        float e0 = t0 + adn; e0 = (e0 > 0.f) ? e0 : 0.2f * e0;
        float ex0 = __expf(e0); ssum += ex0; o += ex0 * b2f(q0);
        float e1 = t1 + adn; e1 = (e1 > 0.f) ? e1 : 0.2f * e1;
        float ex1 = __expf(e1); ssum += ex1; o += ex1 * b2f(q1);
        float e2 = t2 + adn; e2 = (e2 > 0.f) ? e2 : 0.2f * e2;
        float ex2 = __expf(e2); ssum += ex2; o += ex2 * b2f(q2);
        float e3 = t3 + adn; e3 = (e3 > 0.f) ? e3 : 0.2f * e3;
        float ex3 = __expf(e3); ssum += ex3; o += ex3 * b2f(q3);
    }
    for (; k < end; ++k) {
        int s = col[k];
        float e = asrc[s] + adn;
        e = (e > 0.f) ? e : 0.2f * e;
        float ex = __expf(e);
        ssum += ex;
        o += ex * b2f(h[(size_t)s * 64 + l]);
    }
    float v = o / (ssum + 1e-16f) + bias[l];
    v = (v > 0.f) ? v : expm1f(v);   // ELU -> x3[n][l], fp32

    // h3[n][l] = sum_c x3[c] * W3[l][c]  (shuffle-broadcast matvec)
    float acc3 = 0.f;
#pragma unroll
    for (int cb = 0; cb < 8; ++cb) {
        uint4 wv = *(const uint4*)&sW3[l * 68 + cb * 8];
        float wf[8];
        unpack8(wv, wf);
#pragma unroll
        for (int i = 0; i < 8; ++i)
            acc3 += __shfl(v, cb * 8 + i) * wf[i];
    }

    // layer-3 attention coefficients
    float ps = acc3 * a3s[l];
    float pd = acc3 * a3d[l];
#pragma unroll
    for (int off = 32; off; off >>= 1) {
        ps += __shfl_xor(ps, off);
        pd += __shfl_xor(pd, off);
    }
    if (l == 0) { as2[n] = ps; ad2[n] = pd; }
    h3[(size_t)n * 64 + l] = f2b(acc3);
}

// ---------------------------------------------------------------------------
// Layer-3 aggregation + fused classifier: out[n,10] = elu(agg+b3) @ Wc^T + bc
// ---------------------------------------------------------------------------
__global__ __launch_bounds__(256) void k_agg1_cls(const unsigned short* __restrict__ h, // [N,64]
                                                  const float* __restrict__ asrc,       // [N]
                                                  const float* __restrict__ adst,       // [N]
                                                  const int* __restrict__ rowptr,
                                                  const int* __restrict__ col,
                                                  const float* __restrict__ bias,       // [64] b3
                                                  const float* __restrict__ Wc,         // [10,64]
                                                  const float* __restrict__ bc,         // [10]
                                                  float* __restrict__ out_cls) {        // [N,10]
    int n = blockIdx.x * 4 + (threadIdx.x >> 6);
    if (n >= N_NODES) return;
    int l = threadIdx.x & 63;
    int start = rowptr[n], end = rowptr[n + 1];
    float adn = adst[n];

    float ssum = 0.f, o = 0.f;
    int k = start;
    for (; k + 4 <= end; k += 4) {
        int s0 = col[k], s1 = col[k + 1], s2 = col[k + 2], s3 = col[k + 3];
        float t0 = asrc[s0], t1 = asrc[s1], t2 = asrc[s2], t3 = asrc[s3];
        unsigned short q0 = h[(size_t)s0 * 64 + l];
        unsigned short q1 = h[(size_t)s1 * 64 + l];
        unsigned short q2 = h[(size_t)s2 * 64 + l];
        unsigned short q3 = h[(size_t)s3 * 64 + l];
        float e0 = t0 + adn; e0 = (e0 > 0.f) ? e0 : 0.2f * e0;
        float ex0 = __expf(e0); ssum += ex0; o += ex0 * b2f(q0);
        float e1 = t1 + adn; e1 = (e1 > 0.f) ? e1 : 0.2f * e1;
        float ex1 = __expf(e1); ssum += ex1; o += ex1 * b2f(q1);
        float e2 = t2 + adn; e2 = (e2 > 0.f) ? e2 : 0.2f * e2;
        float ex2 = __expf(e2); ssum += ex2; o += ex2 * b2f(q2);
        float e3 = t3 + adn; e3 = (e3 > 0.f) ? e3 : 0.2f * e3;
        float ex3 = __expf(e3); ssum += ex3; o += ex3 * b2f(q3);
    }
    for (; k < end; ++k) {
        int s = col[k];
        float e = asrc[s] + adn;
        e = (e > 0.f) ? e : 0.2f * e;
        float ex = __expf(e);
        ssum += ex;
        o += ex * b2f(h[(size_t)s * 64 + l]);
    }
    float v = o / (ssum + 1e-16f) + bias[l];
    v = (v > 0.f) ? v : expm1f(v);   // ELU
#pragma unroll
    for (int d = 0; d < 10; ++d) {
        float p = v * Wc[d * 64 + l];
#pragma unroll
        for (int off = 32; off; off >>= 1) p += __shfl_xor(p, off);
        if (l == d) out_cls[n * 10 + d] = p + bc[d];
    }
}

// ---------------------------------------------------------------------------
extern "C" void kernel_launch(void* const* d_in, const int* in_sizes, int n_in,
                              void* d_out, int out_size, void* d_ws, size_t ws_size,
                              hipStream_t stream) {
    const float* x    = (const float*)d_in[0];
    const int*   eidx = (const int*)  d_in[1];
    const float* W1   = (const float*)d_in[2];
    const float* a1s  = (const float*)d_in[3];
    const float* a1d  = (const float*)d_in[4];
    const float* b1   = (const float*)d_in[5];
    const float* W2   = (const float*)d_in[6];
    const float* a2s  = (const float*)d_in[7];
    const float* a2d  = (const float*)d_in[8];
    const float* b2   = (const float*)d_in[9];
    const float* W3   = (const float*)d_in[10];
    const float* a3s  = (const float*)d_in[11];
    const float* a3d  = (const float*)d_in[12];
    const float* b3   = (const float*)d_in[13];
    const float* Wc   = (const float*)d_in[14];
    const float* bc   = (const float*)d_in[15];
    float* out = (float*)d_out;

    // Workspace layout: fp32 first (16B alignment), then bf16, then ints
    float* asbuf = (float*)d_ws;                              // N*8
    float* adbuf = asbuf + (size_t)N_NODES * 8;               // N*8
    float* as2   = adbuf + (size_t)N_NODES * 8;               // N  (layer-3 coefs)
    float* ad2   = as2 + N_NODES;                             // N
    unsigned short* h1  = (unsigned short*)(ad2 + N_NODES);   // N*512
    unsigned short* x2  = h1  + (size_t)N_NODES * 512;        // N*512
    unsigned short* h2  = x2  + (size_t)N_NODES * 512;        // N*64
    unsigned short* h3  = h2  + (size_t)N_NODES * 64;         // N*64
    unsigned short* W1b = h3  + (size_t)N_NODES * 64;         // 512*128
    unsigned short* W2b = W1b + 512 * 128;                    // 64*512
    unsigned short* W3b = W2b + 64 * 512;                     // 64*64
    int* ibase  = (int*)(W3b + 64 * 64);
    int* deg    = ibase;                                      // N   (memset)
    int* flag   = deg + N_NODES;                              // 1   (memset)
    int* rowptr = flag + 1;                                   // N+1
    int* cursor = rowptr + N_NODES + 1;                       // N
    int* bsum   = cursor + N_NODES;                           // 256
    int* boff   = bsum + 256;                                 // 256
    int* col    = boff + 256;                                 // ETOT (not memset)
    size_t memset_bytes = (size_t)(N_NODES + 1) * sizeof(int);

    hipMemsetAsync(ibase, 0, memset_bytes, stream);

    dim3 blk(256);
    const int SCAN_BLOCKS = (N_NODES + 255) / 256;   // 196

    // Graph preprocessing (CSR by destination)
    k_detect<<<32, blk, 0, stream>>>(eidx, flag);
    k_degree<<<(ETOT + 255) / 256, blk, 0, stream>>>(eidx, flag, deg);
    k_scan1<<<SCAN_BLOCKS, blk, 0, stream>>>(deg, rowptr, bsum);
    k_scan2<<<1, blk, 0, stream>>>(bsum, boff, rowptr, SCAN_BLOCKS);
    k_scan3<<<SCAN_BLOCKS, blk, 0, stream>>>(rowptr, boff, cursor);
    k_scatter<<<(ETOT + 255) / 256, blk, 0, stream>>>(eidx, flag, cursor, col);

    // Weight casts
    k_cast_w<<<64, blk, 0, stream>>>(W1, W2, W3, W1b, W2b, W3b);

    int mblocks = (N_NODES + 63) / 64;   // 782
    int nblocks = N_NODES / 4;           // 12500 (exact)

    // Layer 1: x[N,128] fp32 -> h1[N,512] (+ attn coefs); agg -> x2
    k_gemm1<<<mblocks, blk, 0, stream>>>(x, W1b, h1, a1s, a1d, asbuf, adbuf, N_NODES);
    k_agg8<<<nblocks, blk, 0, stream>>>(h1, asbuf, adbuf, rowptr, col, b1, x2);

    // Layer 2: x2[N,512] -> h2[N,64] (+ attn coefs)
    k_gemm<<<dim3(1, mblocks), blk, 0, stream>>>(x2, W2b, h2, a2s, a2d, asbuf, adbuf,
                                                 N_NODES, 512);
    // Layer-2 agg fused with layer-3 linear + attn coefs -> h3, as2/ad2
    k_agg1_mid<<<nblocks, blk, 0, stream>>>(h2, asbuf, adbuf, rowptr, col, b2,
                                            W3b, a3s, a3d, h3, as2, ad2);

    // Layer-3 aggregation with fused classifier -> out[N,10]
    k_agg1_cls<<<nblocks, blk, 0, stream>>>(h3, as2, ad2, rowptr, col, b3, Wc, bc, out);
}

// Round 9
// 547.935 us; speedup vs baseline: 1.0297x; 1.0297x over previous
//
#include <hip/hip_runtime.h>
#include <math.h>

#define N_NODES 50000
#define N_EDGES 800000
#define ETOT    (N_EDGES + N_NODES)   // 850000, with self loops

typedef short bf16x8 __attribute__((ext_vector_type(8)));
typedef float f32x4  __attribute__((ext_vector_type(4)));

__device__ __forceinline__ float b2f(unsigned int u16) {   // low 16 bits hold bf16
    return __uint_as_float(u16 << 16);
}
__device__ __forceinline__ unsigned short f2b(float f) {   // RNE
    unsigned int u = __float_as_uint(f);
    u += 0x7fffu + ((u >> 16) & 1u);
    return (unsigned short)(u >> 16);
}
// unpack uint4 (8 bf16) -> 8 floats
__device__ __forceinline__ void unpack8(uint4 v, float* f) {
    f[0] = __uint_as_float(v.x << 16); f[1] = __uint_as_float(v.x & 0xffff0000u);
    f[2] = __uint_as_float(v.y << 16); f[3] = __uint_as_float(v.y & 0xffff0000u);
    f[4] = __uint_as_float(v.z << 16); f[5] = __uint_as_float(v.z & 0xffff0000u);
    f[6] = __uint_as_float(v.w << 16); f[7] = __uint_as_float(v.w & 0xffff0000u);
}

// ---------------------------------------------------------------------------
// Edge-index dtype detection (reference int64 vs harness int32).
// ---------------------------------------------------------------------------
__global__ void k_detect(const int* __restrict__ idx, int* __restrict__ flag) {
    int i = blockIdx.x * blockDim.x + threadIdx.x;   // 8192 threads
    int v = idx[2 * i + 1];
    unsigned long long any = __ballot(v != 0);
    if ((threadIdx.x & 63) == 0 && any) atomicOr(flag, 1);   // 1 => int32 data
}

__device__ __forceinline__ int edge_src(const int* idx, int e, int is32) {
    return is32 ? idx[e] : idx[2 * e];
}
__device__ __forceinline__ int edge_dst(const int* idx, int e, int is32) {
    return is32 ? idx[N_EDGES + e] : idx[2 * (N_EDGES + e)];
}

// ---------------------------------------------------------------------------
// CSR build: degree -> 3-kernel scan -> scatter
// ---------------------------------------------------------------------------
__global__ void k_degree(const int* __restrict__ idx, const int* __restrict__ flag,
                         int* __restrict__ deg) {
    int e = blockIdx.x * blockDim.x + threadIdx.x;
    if (e >= ETOT) return;
    int is32 = *flag;
    int d = (e < N_EDGES) ? edge_dst(idx, e, is32) : (e - N_EDGES);
    atomicAdd(&deg[d], 1);
}

__global__ __launch_bounds__(256) void k_scan1(const int* __restrict__ deg,
                                               int* __restrict__ rowptr,
                                               int* __restrict__ bsum) {
    __shared__ int sd[256];
    int t = threadIdx.x;
    int i = blockIdx.x * 256 + t;
    int v = (i < N_NODES) ? deg[i] : 0;
    sd[t] = v;
    __syncthreads();
#pragma unroll
    for (int off = 1; off < 256; off <<= 1) {
        int a = (t >= off) ? sd[t - off] : 0;
        __syncthreads();
        sd[t] += a;
        __syncthreads();
    }
    if (i < N_NODES) rowptr[i] = sd[t] - v;    // block-local exclusive
    if (t == 255) bsum[blockIdx.x] = sd[255];
}

__global__ __launch_bounds__(256) void k_scan2(int* __restrict__ bsum,
                                               int* __restrict__ boff,
                                               int* __restrict__ rowptr,
                                               int nb) {
    __shared__ int sd[256];
    int t = threadIdx.x;
    int v = (t < nb) ? bsum[t] : 0;
    sd[t] = v;
    __syncthreads();
#pragma unroll
    for (int off = 1; off < 256; off <<= 1) {
        int a = (t >= off) ? sd[t - off] : 0;
        __syncthreads();
        sd[t] += a;
        __syncthreads();
    }
    boff[t] = sd[t] - v;                        // exclusive
    if (t == 255) rowptr[N_NODES] = sd[255];
}

__global__ __launch_bounds__(256) void k_scan3(int* __restrict__ rowptr,
                                               const int* __restrict__ boff,
                                               int* __restrict__ cursor) {
    int i = blockIdx.x * 256 + threadIdx.x;
    if (i >= N_NODES) return;
    int r = rowptr[i] + boff[blockIdx.x];
    rowptr[i] = r;
    cursor[i] = r;
}

__global__ void k_scatter(const int* __restrict__ idx, const int* __restrict__ flag,
                          int* __restrict__ cursor, int* __restrict__ col) {
    int e = blockIdx.x * blockDim.x + threadIdx.x;
    if (e >= ETOT) return;
    int is32 = *flag;
    int s, d;
    if (e < N_EDGES) { s = edge_src(idx, e, is32); d = edge_dst(idx, e, is32); }
    else             { s = d = e - N_EDGES; }
    int pos = atomicAdd(&cursor[d], 1);
    col[pos] = s;
}

// ---------------------------------------------------------------------------
// fp32 -> bf16 cast for weights (x consumed fp32 by gemm1 directly)
// ---------------------------------------------------------------------------
__global__ void k_cast_w(const float* __restrict__ w1, const float* __restrict__ w2,
                         const float* __restrict__ w3,
                         unsigned short* __restrict__ o1, unsigned short* __restrict__ o2,
                         unsigned short* __restrict__ o3) {
    int i = blockIdx.x * blockDim.x + threadIdx.x;
    if (i < 512 * 128 / 4) {
        float4 v = ((const float4*)w1)[i];
        ushort2* o = (ushort2*)(o1 + i * 4);
        o[0] = make_ushort2(f2b(v.x), f2b(v.y));
        o[1] = make_ushort2(f2b(v.z), f2b(v.w));
    }
    if (i < 64 * 512 / 4) {
        float4 v = ((const float4*)w2)[i];
        ushort2* o = (ushort2*)(o2 + i * 4);
        o[0] = make_ushort2(f2b(v.x), f2b(v.y));
        o[1] = make_ushort2(f2b(v.z), f2b(v.w));
    }
    if (i < 64 * 64 / 4) {
        float4 v = ((const float4*)w3)[i];
        ushort2* o = (ushort2*)(o3 + i * 4);
        o[0] = make_ushort2(f2b(v.x), f2b(v.y));
        o[1] = make_ushort2(f2b(v.z), f2b(v.w));
    }
}

// ---------------------------------------------------------------------------
// bf16 MFMA GEMM (R6-measured-best shape): C[M,Nout] = A[M,K] @ W[Nout,K]^T.
// 64x64 block tile, 256 threads = 4 waves; wave w owns cols [16w,16w+16);
// 4 row-tiles of 16 per wave via mfma_f32_16x16x32_bf16. K % 32 == 0.
// AFP32: A read fp32 (layer 1), converted during staging.
// Epilogue computes attention coefficients from fp32 acc (col block = head).
// ---------------------------------------------------------------------------
template<int AFP32>
__global__ __launch_bounds__(256) void k_gemm(const float* __restrict__ Af,
                                              const unsigned short* __restrict__ Ab,
                                              const unsigned short* __restrict__ W,
                                              unsigned short* __restrict__ C,
                                              const float* __restrict__ a_src,
                                              const float* __restrict__ a_dst,
                                              float* __restrict__ asb,
                                              float* __restrict__ adb,
                                              int M, int K, int Nout, int Hstr) {
    __shared__ unsigned short As[64 * 40];   // row stride 40 shorts (80 B)
    __shared__ unsigned short Bs[64 * 40];
    __shared__ float red_s[4][64];
    __shared__ float red_d[4][64];
    int t = threadIdx.x;
    int w = t >> 6, l = t & 63;
    int quad = l >> 4, lm = l & 15;
    int m0 = blockIdx.y * 64, n0 = blockIdx.x * 64;
    int hd = blockIdx.x;
    int lr = t >> 2;            // staging row 0..63
    int lc = (t & 3) * 8;       // staging col offset 0/8/16/24

    f32x4 acc[4];
#pragma unroll
    for (int r = 0; r < 4; ++r) acc[r] = (f32x4){0.f, 0.f, 0.f, 0.f};

    for (int k0 = 0; k0 < K; k0 += 32) {
        int m = m0 + lr;
        if (AFP32) {
            float4 a0 = {0.f,0.f,0.f,0.f}, a1 = {0.f,0.f,0.f,0.f};
            if (m < M) {
                const float4* ap = (const float4*)(Af + (size_t)m * K + k0 + lc);
                a0 = ap[0]; a1 = ap[1];
            }
            unsigned int u0 = (unsigned int)f2b(a0.x) | ((unsigned int)f2b(a0.y) << 16);
            unsigned int u1 = (unsigned int)f2b(a0.z) | ((unsigned int)f2b(a0.w) << 16);
            unsigned int u2 = (unsigned int)f2b(a1.x) | ((unsigned int)f2b(a1.y) << 16);
            unsigned int u3 = (unsigned int)f2b(a1.z) | ((unsigned int)f2b(a1.w) << 16);
            *(uint4*)&As[lr * 40 + lc] = make_uint4(u0, u1, u2, u3);
        } else {
            uint4 av = make_uint4(0, 0, 0, 0);
            if (m < M) av = *(const uint4*)(Ab + (size_t)m * K + k0 + lc);
            *(uint4*)&As[lr * 40 + lc] = av;
        }
        uint4 bv = *(const uint4*)(W + (size_t)(n0 + lr) * K + k0 + lc);
        *(uint4*)&Bs[lr * 40 + lc] = bv;
        __syncthreads();

        bf16x8 bfrag = *(const bf16x8*)&Bs[(w * 16 + lm) * 40 + quad * 8];
#pragma unroll
        for (int r = 0; r < 4; ++r) {
            bf16x8 afrag = *(const bf16x8*)&As[(r * 16 + lm) * 40 + quad * 8];
            acc[r] = __builtin_amdgcn_mfma_f32_16x16x32_bf16(afrag, bfrag, acc[r], 0, 0, 0);
        }
        __syncthreads();
    }

    // C store (bf16)
#pragma unroll
    for (int r = 0; r < 4; ++r)
#pragma unroll
        for (int g = 0; g < 4; ++g) {
            int m = m0 + r * 16 + quad * 4 + g;
            if (m < M) C[(size_t)m * Nout + n0 + w * 16 + lm] = f2b(acc[r][g]);
        }

    // Attention-coefficient epilogue (fp32 accumulators)
    float as = a_src[hd * 64 + w * 16 + lm];
    float ad = a_dst[hd * 64 + w * 16 + lm];
#pragma unroll
    for (int r = 0; r < 4; ++r) {
#pragma unroll
        for (int g = 0; g < 4; ++g) {
            float vs = acc[r][g] * as;
            float vd = acc[r][g] * ad;
#pragma unroll
            for (int off = 1; off < 16; off <<= 1) {
                vs += __shfl_xor(vs, off);
                vd += __shfl_xor(vd, off);
            }
            if (lm == 0) {
                red_s[w][r * 16 + quad * 4 + g] = vs;
                red_d[w][r * 16 + quad * 4 + g] = vd;
            }
        }
    }
    __syncthreads();
    if (t < 64) {
        float vs = red_s[0][t] + red_s[1][t] + red_s[2][t] + red_s[3][t];
        float vd = red_d[0][t] + red_d[1][t] + red_d[2][t] + red_d[3][t];
        int m = m0 + t;
        if (m < M) {
            asb[(size_t)m * Hstr + hd] = vs;
            adb[(size_t)m * Hstr + hd] = vd;
        }
    }
}

// ---------------------------------------------------------------------------
// Fused segment-softmax + aggregation, H=8, C=64 (layer 1), bf16 h.
// Single pass, no max subtraction (|e| <= ~2 analytically). Unrolled x4.
// ---------------------------------------------------------------------------
__global__ __launch_bounds__(256) void k_agg8(const unsigned short* __restrict__ h, // [N,512]
                                              const float* __restrict__ asrc,       // [N,8]
                                              const float* __restrict__ adst,       // [N,8]
                                              const int* __restrict__ rowptr,
                                              const int* __restrict__ col,
                                              const float* __restrict__ bias,       // [512]
                                              unsigned short* __restrict__ out) {   // [N,512]
    int n = blockIdx.x * 4 + (threadIdx.x >> 6);
    if (n >= N_NODES) return;
    int l = threadIdx.x & 63;
    int j = l >> 3;
    int start = rowptr[n], end = rowptr[n + 1];
    float adn = adst[n * 8 + j];

    float ssum = 0.f;
    float o[8] = {0.f, 0.f, 0.f, 0.f, 0.f, 0.f, 0.f, 0.f};
    int k = start;
    for (; k + 4 <= end; k += 4) {
        int s0 = col[k], s1 = col[k + 1], s2 = col[k + 2], s3 = col[k + 3];
        float t0 = asrc[s0 * 8 + j], t1 = asrc[s1 * 8 + j];
        float t2 = asrc[s2 * 8 + j], t3 = asrc[s3 * 8 + j];
        uint4 hv0 = *(const uint4*)(h + (size_t)s0 * 512 + l * 8);
        uint4 hv1 = *(const uint4*)(h + (size_t)s1 * 512 + l * 8);
        uint4 hv2 = *(const uint4*)(h + (size_t)s2 * 512 + l * 8);
        uint4 hv3 = *(const uint4*)(h + (size_t)s3 * 512 + l * 8);
        float f[8];
        float e0 = t0 + adn; e0 = (e0 > 0.f) ? e0 : 0.2f * e0;
        float ex0 = __expf(e0); ssum += ex0;
        unpack8(hv0, f);
#pragma unroll
        for (int i = 0; i < 8; ++i) o[i] += ex0 * f[i];
        float e1 = t1 + adn; e1 = (e1 > 0.f) ? e1 : 0.2f * e1;
        float ex1 = __expf(e1); ssum += ex1;
        unpack8(hv1, f);
#pragma unroll
        for (int i = 0; i < 8; ++i) o[i] += ex1 * f[i];
        float e2 = t2 + adn; e2 = (e2 > 0.f) ? e2 : 0.2f * e2;
        float ex2 = __expf(e2); ssum += ex2;
        unpack8(hv2, f);
#pragma unroll
        for (int i = 0; i < 8; ++i) o[i] += ex2 * f[i];
        float e3 = t3 + adn; e3 = (e3 > 0.f) ? e3 : 0.2f * e3;
        float ex3 = __expf(e3); ssum += ex3;
        unpack8(hv3, f);
#pragma unroll
        for (int i = 0; i < 8; ++i) o[i] += ex3 * f[i];
    }
    for (; k < end; ++k) {
        int s = col[k];
        float e = asrc[s * 8 + j] + adn;
        e = (e > 0.f) ? e : 0.2f * e;
        float ex = __expf(e);
        ssum += ex;
        uint4 hv = *(const uint4*)(h + (size_t)s * 512 + l * 8);
        float f[8];
        unpack8(hv, f);
#pragma unroll
        for (int i = 0; i < 8; ++i) o[i] += ex * f[i];
    }
    float inv = 1.f / (ssum + 1e-16f);
    unsigned int p[4];
#pragma unroll
    for (int i = 0; i < 4; ++i) {
        float v0 = o[2 * i] * inv + bias[l * 8 + 2 * i];
        float v1 = o[2 * i + 1] * inv + bias[l * 8 + 2 * i + 1];
        v0 = (v0 > 0.f) ? v0 : expm1f(v0);
        v1 = (v1 > 0.f) ? v1 : expm1f(v1);
        p[i] = (unsigned int)f2b(v0) | ((unsigned int)f2b(v1) << 16);
    }
    *(uint4*)(out + (size_t)n * 512 + l * 8) = make_uint4(p[0], p[1], p[2], p[3]);
}

// ---------------------------------------------------------------------------
// Layer-2 aggregation + FUSED layer-3 linear (64x64 matvec) + layer-3 attn
// coefficients. One wave per dst node; lane = channel. Aggregated, biased,
// ELU'd v (= x3[n][l], fp32, no bf16 roundtrip) -> W3 matvec via
// shuffle-broadcast with LDS-resident W3 -> h3 + a3 coefs.
// Writes layer-3 coefs to as2/ad2 (separate from asrc/adst being read).
// Grid exactly N/4 blocks, no early return (barrier-safe; N % 4 == 0).
// ---------------------------------------------------------------------------
__global__ __launch_bounds__(256) void k_agg1_mid(const unsigned short* __restrict__ h, // [N,64]
                                                  const float* __restrict__ asrc,       // [N]
                                                  const float* __restrict__ adst,       // [N]
                                                  const int* __restrict__ rowptr,
                                                  const int* __restrict__ col,
                                                  const float* __restrict__ bias,       // [64] b2
                                                  const unsigned short* __restrict__ W3b,// [64,64]
                                                  const float* __restrict__ a3s,        // [64]
                                                  const float* __restrict__ a3d,        // [64]
                                                  unsigned short* __restrict__ h3,      // [N,64]
                                                  float* __restrict__ as2,              // [N]
                                                  float* __restrict__ ad2) {            // [N]
    __shared__ unsigned short sW3[64 * 68];   // stride 68: 2-way bank alias (free)
    int t = threadIdx.x;
    {
        int r0 = t >> 2, c0 = (t & 3) * 16;
        *(uint4*)&sW3[r0 * 68 + c0]     = *(const uint4*)(W3b + r0 * 64 + c0);
        *(uint4*)&sW3[r0 * 68 + c0 + 8] = *(const uint4*)(W3b + r0 * 64 + c0 + 8);
    }
    __syncthreads();

    int n = blockIdx.x * 4 + (t >> 6);
    int l = t & 63;
    int start = rowptr[n], end = rowptr[n + 1];
    float adn = adst[n];

    float ssum = 0.f, o = 0.f;
    int k = start;
    for (; k + 4 <= end; k += 4) {
        int s0 = col[k], s1 = col[k + 1], s2 = col[k + 2], s3 = col[k + 3];
        float t0 = asrc[s0], t1 = asrc[s1], t2 = asrc[s2], t3 = asrc[s3];
        unsigned short q0 = h[(size_t)s0 * 64 + l];
        unsigned short q1 = h[(size_t)s1 * 64 + l];
        unsigned short q2 = h[(size_t)s2 * 64 + l];
        unsigned short q3 = h[(size_t)s3 * 64 + l];
        float e0 = t0 + adn; e0 = (e0 > 0.f) ? e0 : 0.2f * e0;
        float ex0 = __expf(e0); ssum += ex0; o += ex0 * b2f(q0);
        float e1 = t1 + adn; e1 = (e1 > 0.f) ? e1 : 0.2f * e1;
        float ex1 = __expf(e1); ssum += ex1; o += ex1 * b2f(q1);
        float e2 = t2 + adn; e2 = (e2 > 0.f) ? e2 : 0.2f * e2;
        float ex2 = __expf(e2); ssum += ex2; o += ex2 * b2f(q2);
        float e3 = t3 + adn; e3 = (e3 > 0.f) ? e3 : 0.2f * e3;
        float ex3 = __expf(e3); ssum += ex3; o += ex3 * b2f(q3);
    }
    for (; k < end; ++k) {
        int s = col[k];
        float e = asrc[s] + adn;
        e = (e > 0.f) ? e : 0.2f * e;
        float ex = __expf(e);
        ssum += ex;
        o += ex * b2f(h[(size_t)s * 64 + l]);
    }
    float v = o / (ssum + 1e-16f) + bias[l];
    v = (v > 0.f) ? v : expm1f(v);   // ELU -> x3[n][l], fp32

    // h3[n][l] = sum_c x3[c] * W3[l][c]  (shuffle-broadcast matvec)
    float acc3 = 0.f;
#pragma unroll
    for (int cb = 0; cb < 8; ++cb) {
        uint4 wv = *(const uint4*)&sW3[l * 68 + cb * 8];
        float wf[8];
        unpack8(wv, wf);
#pragma unroll
        for (int i = 0; i < 8; ++i)
            acc3 += __shfl(v, cb * 8 + i) * wf[i];
    }

    // layer-3 attention coefficients
    float ps = acc3 * a3s[l];
    float pd = acc3 * a3d[l];
#pragma unroll
    for (int off = 32; off; off >>= 1) {
        ps += __shfl_xor(ps, off);
        pd += __shfl_xor(pd, off);
    }
    if (l == 0) { as2[n] = ps; ad2[n] = pd; }
    h3[(size_t)n * 64 + l] = f2b(acc3);
}

// ---------------------------------------------------------------------------
// Layer-3 aggregation + fused classifier: out[n,10] = elu(agg+b3) @ Wc^T + bc
// ---------------------------------------------------------------------------
__global__ __launch_bounds__(256) void k_agg1_cls(const unsigned short* __restrict__ h, // [N,64]
                                                  const float* __restrict__ asrc,       // [N]
                                                  const float* __restrict__ adst,       // [N]
                                                  const int* __restrict__ rowptr,
                                                  const int* __restrict__ col,
                                                  const float* __restrict__ bias,       // [64] b3
                                                  const float* __restrict__ Wc,         // [10,64]
                                                  const float* __restrict__ bc,         // [10]
                                                  float* __restrict__ out_cls) {        // [N,10]
    int n = blockIdx.x * 4 + (threadIdx.x >> 6);
    if (n >= N_NODES) return;
    int l = threadIdx.x & 63;
    int start = rowptr[n], end = rowptr[n + 1];
    float adn = adst[n];

    float ssum = 0.f, o = 0.f;
    int k = start;
    for (; k + 4 <= end; k += 4) {
        int s0 = col[k], s1 = col[k + 1], s2 = col[k + 2], s3 = col[k + 3];
        float t0 = asrc[s0], t1 = asrc[s1], t2 = asrc[s2], t3 = asrc[s3];
        unsigned short q0 = h[(size_t)s0 * 64 + l];
        unsigned short q1 = h[(size_t)s1 * 64 + l];
        unsigned short q2 = h[(size_t)s2 * 64 + l];
        unsigned short q3 = h[(size_t)s3 * 64 + l];
        float e0 = t0 + adn; e0 = (e0 > 0.f) ? e0 : 0.2f * e0;
        float ex0 = __expf(e0); ssum += ex0; o += ex0 * b2f(q0);
        float e1 = t1 + adn; e1 = (e1 > 0.f) ? e1 : 0.2f * e1;
        float ex1 = __expf(e1); ssum += ex1; o += ex1 * b2f(q1);
        float e2 = t2 + adn; e2 = (e2 > 0.f) ? e2 : 0.2f * e2;
        float ex2 = __expf(e2); ssum += ex2; o += ex2 * b2f(q2);
        float e3 = t3 + adn; e3 = (e3 > 0.f) ? e3 : 0.2f * e3;
        float ex3 = __expf(e3); ssum += ex3; o += ex3 * b2f(q3);
    }
    for (; k < end; ++k) {
        int s = col[k];
        float e = asrc[s] + adn;
        e = (e > 0.f) ? e : 0.2f * e;
        float ex = __expf(e);
        ssum += ex;
        o += ex * b2f(h[(size_t)s * 64 + l]);
    }
    float v = o / (ssum + 1e-16f) + bias[l];
    v = (v > 0.f) ? v : expm1f(v);   // ELU
#pragma unroll
    for (int d = 0; d < 10; ++d) {
        float p = v * Wc[d * 64 + l];
#pragma unroll
        for (int off = 32; off; off >>= 1) p += __shfl_xor(p, off);
        if (l == d) out_cls[n * 10 + d] = p + bc[d];
    }
}

// ---------------------------------------------------------------------------
extern "C" void kernel_launch(void* const* d_in, const int* in_sizes, int n_in,
                              void* d_out, int out_size, void* d_ws, size_t ws_size,
                              hipStream_t stream) {
    const float* x    = (const float*)d_in[0];
    const int*   eidx = (const int*)  d_in[1];
    const float* W1   = (const float*)d_in[2];
    const float* a1s  = (const float*)d_in[3];
    const float* a1d  = (const float*)d_in[4];
    const float* b1   = (const float*)d_in[5];
    const float* W2   = (const float*)d_in[6];
    const float* a2s  = (const float*)d_in[7];
    const float* a2d  = (const float*)d_in[8];
    const float* b2   = (const float*)d_in[9];
    const float* W3   = (const float*)d_in[10];
    const float* a3s  = (const float*)d_in[11];
    const float* a3d  = (const float*)d_in[12];
    const float* b3   = (const float*)d_in[13];
    const float* Wc   = (const float*)d_in[14];
    const float* bc   = (const float*)d_in[15];
    float* out = (float*)d_out;

    // Workspace layout: fp32 first (16B alignment), then bf16, then ints
    float* asbuf = (float*)d_ws;                              // N*8
    float* adbuf = asbuf + (size_t)N_NODES * 8;               // N*8
    float* as2   = adbuf + (size_t)N_NODES * 8;               // N  (layer-3 coefs)
    float* ad2   = as2 + N_NODES;                             // N
    unsigned short* h1  = (unsigned short*)(ad2 + N_NODES);   // N*512
    unsigned short* x2  = h1  + (size_t)N_NODES * 512;        // N*512
    unsigned short* h2  = x2  + (size_t)N_NODES * 512;        // N*64
    unsigned short* h3  = h2  + (size_t)N_NODES * 64;         // N*64
    unsigned short* W1b = h3  + (size_t)N_NODES * 64;         // 512*128
    unsigned short* W2b = W1b + 512 * 128;                    // 64*512
    unsigned short* W3b = W2b + 64 * 512;                     // 64*64
    int* ibase  = (int*)(W3b + 64 * 64);
    int* deg    = ibase;                                      // N   (memset)
    int* flag   = deg + N_NODES;                              // 1   (memset)
    int* rowptr = flag + 1;                                   // N+1
    int* cursor = rowptr + N_NODES + 1;                       // N
    int* bsum   = cursor + N_NODES;                           // 256
    int* boff   = bsum + 256;                                 // 256
    int* col    = boff + 256;                                 // ETOT (not memset)
    size_t memset_bytes = (size_t)(N_NODES + 1) * sizeof(int);

    hipMemsetAsync(ibase, 0, memset_bytes, stream);

    dim3 blk(256);
    const int SCAN_BLOCKS = (N_NODES + 255) / 256;   // 196

    // Graph preprocessing (CSR by destination)
    k_detect<<<32, blk, 0, stream>>>(eidx, flag);
    k_degree<<<(ETOT + 255) / 256, blk, 0, stream>>>(eidx, flag, deg);
    k_scan1<<<SCAN_BLOCKS, blk, 0, stream>>>(deg, rowptr, bsum);
    k_scan2<<<1, blk, 0, stream>>>(bsum, boff, rowptr, SCAN_BLOCKS);
    k_scan3<<<SCAN_BLOCKS, blk, 0, stream>>>(rowptr, boff, cursor);
    k_scatter<<<(ETOT + 255) / 256, blk, 0, stream>>>(eidx, flag, cursor, col);

    // Weight casts
    k_cast_w<<<64, blk, 0, stream>>>(W1, W2, W3, W1b, W2b, W3b);

    int mblocks = (N_NODES + 63) / 64;   // 782
    int nblocks = N_NODES / 4;           // 12500 (exact)

    // Layer 1: x[N,128] fp32 -> h1[N,512] (+ attn coefs); agg -> x2
    k_gemm<1><<<dim3(8, mblocks), blk, 0, stream>>>(x, (const unsigned short*)0, W1b, h1,
                                                    a1s, a1d, asbuf, adbuf,
                                                    N_NODES, 128, 512, 8);
    k_agg8<<<nblocks, blk, 0, stream>>>(h1, asbuf, adbuf, rowptr, col, b1, x2);

    // Layer 2: x2[N,512] -> h2[N,64] (+ attn coefs)
    k_gemm<0><<<dim3(1, mblocks), blk, 0, stream>>>((const float*)0, x2, W2b, h2,
                                                    a2s, a2d, asbuf, adbuf,
                                                    N_NODES, 512, 64, 1);
    // Layer-2 agg fused with layer-3 linear + attn coefs -> h3, as2/ad2
    k_agg1_mid<<<nblocks, blk, 0, stream>>>(h2, asbuf, adbuf, rowptr, col, b2,
                                            W3b, a3s, a3d, h3, as2, ad2);

    // Layer-3 aggregation with fused classifier -> out[N,10]
    k_agg1_cls<<<nblocks, blk, 0, stream>>>(h3, as2, ad2, rowptr, col, b3, Wc, bc, out);
}

// Round 10
// 509.674 us; speedup vs baseline: 1.1070x; 1.0751x over previous
//
#include <hip/hip_runtime.h>
#include <math.h>

#define N_NODES 50000
#define N_EDGES 800000
#define ETOT    (N_EDGES + N_NODES)   // 850000, with self loops

typedef short bf16x8 __attribute__((ext_vector_type(8)));
typedef float f32x4  __attribute__((ext_vector_type(4)));

__device__ __forceinline__ float b2f(unsigned int u16) {   // low 16 bits hold bf16
    return __uint_as_float(u16 << 16);
}
__device__ __forceinline__ unsigned short f2b(float f) {   // RNE
    unsigned int u = __float_as_uint(f);
    u += 0x7fffu + ((u >> 16) & 1u);
    return (unsigned short)(u >> 16);
}
// unpack uint4 (8 bf16) -> 8 floats
__device__ __forceinline__ void unpack8(uint4 v, float* f) {
    f[0] = __uint_as_float(v.x << 16); f[1] = __uint_as_float(v.x & 0xffff0000u);
    f[2] = __uint_as_float(v.y << 16); f[3] = __uint_as_float(v.y & 0xffff0000u);
    f[4] = __uint_as_float(v.z << 16); f[5] = __uint_as_float(v.z & 0xffff0000u);
    f[6] = __uint_as_float(v.w << 16); f[7] = __uint_as_float(v.w & 0xffff0000u);
}

// ---------------------------------------------------------------------------
// Prep: zero deg+flag (replaces memset) and cast W1/W2/W3 fp32->bf16.
// Grid 196x256 (covers N zeroing and all cast ranges).
// ---------------------------------------------------------------------------
__global__ __launch_bounds__(256) void k_prep(const float* __restrict__ w1,
                                              const float* __restrict__ w2,
                                              const float* __restrict__ w3,
                                              unsigned short* __restrict__ o1,
                                              unsigned short* __restrict__ o2,
                                              unsigned short* __restrict__ o3,
                                              int* __restrict__ deg,
                                              int* __restrict__ flag) {
    int i = blockIdx.x * 256 + threadIdx.x;
    if (i < N_NODES) deg[i] = 0;
    if (i == 0) *flag = 0;
    if (i < 512 * 128 / 4) {
        float4 v = ((const float4*)w1)[i];
        ushort2* o = (ushort2*)(o1 + i * 4);
        o[0] = make_ushort2(f2b(v.x), f2b(v.y));
        o[1] = make_ushort2(f2b(v.z), f2b(v.w));
    }
    if (i < 64 * 512 / 4) {
        float4 v = ((const float4*)w2)[i];
        ushort2* o = (ushort2*)(o2 + i * 4);
        o[0] = make_ushort2(f2b(v.x), f2b(v.y));
        o[1] = make_ushort2(f2b(v.z), f2b(v.w));
    }
    if (i < 64 * 64 / 4) {
        float4 v = ((const float4*)w3)[i];
        ushort2* o = (ushort2*)(o3 + i * 4);
        o[0] = make_ushort2(f2b(v.x), f2b(v.y));
        o[1] = make_ushort2(f2b(v.z), f2b(v.w));
    }
}

// ---------------------------------------------------------------------------
// Edge-index dtype detection (reference int64 vs harness int32).
// ---------------------------------------------------------------------------
__global__ void k_detect(const int* __restrict__ idx, int* __restrict__ flag) {
    int i = blockIdx.x * blockDim.x + threadIdx.x;   // 8192 threads
    int v = idx[2 * i + 1];
    unsigned long long any = __ballot(v != 0);
    if ((threadIdx.x & 63) == 0 && any) atomicOr(flag, 1);   // 1 => int32 data
}

__device__ __forceinline__ int edge_src(const int* idx, int e, int is32) {
    return is32 ? idx[e] : idx[2 * e];
}
__device__ __forceinline__ int edge_dst(const int* idx, int e, int is32) {
    return is32 ? idx[N_EDGES + e] : idx[2 * (N_EDGES + e)];
}

// ---------------------------------------------------------------------------
// CSR build: degree -> 3-kernel scan -> scatter
// ---------------------------------------------------------------------------
__global__ void k_degree(const int* __restrict__ idx, const int* __restrict__ flag,
                         int* __restrict__ deg) {
    int e = blockIdx.x * blockDim.x + threadIdx.x;
    if (e >= ETOT) return;
    int is32 = *flag;
    int d = (e < N_EDGES) ? edge_dst(idx, e, is32) : (e - N_EDGES);
    atomicAdd(&deg[d], 1);
}

__global__ __launch_bounds__(256) void k_scan1(const int* __restrict__ deg,
                                               int* __restrict__ rowptr,
                                               int* __restrict__ bsum) {
    __shared__ int sd[256];
    int t = threadIdx.x;
    int i = blockIdx.x * 256 + t;
    int v = (i < N_NODES) ? deg[i] : 0;
    sd[t] = v;
    __syncthreads();
#pragma unroll
    for (int off = 1; off < 256; off <<= 1) {
        int a = (t >= off) ? sd[t - off] : 0;
        __syncthreads();
        sd[t] += a;
        __syncthreads();
    }
    if (i < N_NODES) rowptr[i] = sd[t] - v;    // block-local exclusive
    if (t == 255) bsum[blockIdx.x] = sd[255];
}

__global__ __launch_bounds__(256) void k_scan2(int* __restrict__ bsum,
                                               int* __restrict__ boff,
                                               int* __restrict__ rowptr,
                                               int nb) {
    __shared__ int sd[256];
    int t = threadIdx.x;
    int v = (t < nb) ? bsum[t] : 0;
    sd[t] = v;
    __syncthreads();
#pragma unroll
    for (int off = 1; off < 256; off <<= 1) {
        int a = (t >= off) ? sd[t - off] : 0;
        __syncthreads();
        sd[t] += a;
        __syncthreads();
    }
    boff[t] = sd[t] - v;                        // exclusive
    if (t == 255) rowptr[N_NODES] = sd[255];
}

__global__ __launch_bounds__(256) void k_scan3(int* __restrict__ rowptr,
                                               const int* __restrict__ boff,
                                               int* __restrict__ cursor) {
    int i = blockIdx.x * 256 + threadIdx.x;
    if (i >= N_NODES) return;
    int r = rowptr[i] + boff[blockIdx.x];
    rowptr[i] = r;
    cursor[i] = r;
}

__global__ void k_scatter(const int* __restrict__ idx, const int* __restrict__ flag,
                          int* __restrict__ cursor, int* __restrict__ col) {
    int e = blockIdx.x * blockDim.x + threadIdx.x;
    if (e >= ETOT) return;
    int is32 = *flag;
    int s, d;
    if (e < N_EDGES) { s = edge_src(idx, e, is32); d = edge_dst(idx, e, is32); }
    else             { s = d = e - N_EDGES; }
    int pos = atomicAdd(&cursor[d], 1);
    col[pos] = s;
}

// ---------------------------------------------------------------------------
// bf16 MFMA GEMM (R6-measured-best shape): C[M,Nout] = A[M,K] @ W[Nout,K]^T.
// 64x64 block tile, 256 threads = 4 waves; wave w owns cols [16w,16w+16);
// 4 row-tiles of 16 per wave via mfma_f32_16x16x32_bf16. K % 32 == 0.
// AFP32: A read fp32 (layer 1), converted during staging.
// Epilogue computes attention coefficients from fp32 acc (col block = head).
// ---------------------------------------------------------------------------
template<int AFP32>
__global__ __launch_bounds__(256) void k_gemm(const float* __restrict__ Af,
                                              const unsigned short* __restrict__ Ab,
                                              const unsigned short* __restrict__ W,
                                              unsigned short* __restrict__ C,
                                              const float* __restrict__ a_src,
                                              const float* __restrict__ a_dst,
                                              float* __restrict__ asb,
                                              float* __restrict__ adb,
                                              int M, int K, int Nout, int Hstr) {
    __shared__ unsigned short As[64 * 40];   // row stride 40 shorts (80 B)
    __shared__ unsigned short Bs[64 * 40];
    __shared__ float red_s[4][64];
    __shared__ float red_d[4][64];
    int t = threadIdx.x;
    int w = t >> 6, l = t & 63;
    int quad = l >> 4, lm = l & 15;
    int m0 = blockIdx.y * 64, n0 = blockIdx.x * 64;
    int hd = blockIdx.x;
    int lr = t >> 2;            // staging row 0..63
    int lc = (t & 3) * 8;       // staging col offset 0/8/16/24

    f32x4 acc[4];
#pragma unroll
    for (int r = 0; r < 4; ++r) acc[r] = (f32x4){0.f, 0.f, 0.f, 0.f};

    for (int k0 = 0; k0 < K; k0 += 32) {
        int m = m0 + lr;
        if (AFP32) {
            float4 a0 = {0.f,0.f,0.f,0.f}, a1 = {0.f,0.f,0.f,0.f};
            if (m < M) {
                const float4* ap = (const float4*)(Af + (size_t)m * K + k0 + lc);
                a0 = ap[0]; a1 = ap[1];
            }
            unsigned int u0 = (unsigned int)f2b(a0.x) | ((unsigned int)f2b(a0.y) << 16);
            unsigned int u1 = (unsigned int)f2b(a0.z) | ((unsigned int)f2b(a0.w) << 16);
            unsigned int u2 = (unsigned int)f2b(a1.x) | ((unsigned int)f2b(a1.y) << 16);
            unsigned int u3 = (unsigned int)f2b(a1.z) | ((unsigned int)f2b(a1.w) << 16);
            *(uint4*)&As[lr * 40 + lc] = make_uint4(u0, u1, u2, u3);
        } else {
            uint4 av = make_uint4(0, 0, 0, 0);
            if (m < M) av = *(const uint4*)(Ab + (size_t)m * K + k0 + lc);
            *(uint4*)&As[lr * 40 + lc] = av;
        }
        uint4 bv = *(const uint4*)(W + (size_t)(n0 + lr) * K + k0 + lc);
        *(uint4*)&Bs[lr * 40 + lc] = bv;
        __syncthreads();

        bf16x8 bfrag = *(const bf16x8*)&Bs[(w * 16 + lm) * 40 + quad * 8];
#pragma unroll
        for (int r = 0; r < 4; ++r) {
            bf16x8 afrag = *(const bf16x8*)&As[(r * 16 + lm) * 40 + quad * 8];
            acc[r] = __builtin_amdgcn_mfma_f32_16x16x32_bf16(afrag, bfrag, acc[r], 0, 0, 0);
        }
        __syncthreads();
    }

    // C store (bf16)
#pragma unroll
    for (int r = 0; r < 4; ++r)
#pragma unroll
        for (int g = 0; g < 4; ++g) {
            int m = m0 + r * 16 + quad * 4 + g;
            if (m < M) C[(size_t)m * Nout + n0 + w * 16 + lm] = f2b(acc[r][g]);
        }

    // Attention-coefficient epilogue (fp32 accumulators)
    float as = a_src[hd * 64 + w * 16 + lm];
    float ad = a_dst[hd * 64 + w * 16 + lm];
#pragma unroll
    for (int r = 0; r < 4; ++r) {
#pragma unroll
        for (int g = 0; g < 4; ++g) {
            float vs = acc[r][g] * as;
            float vd = acc[r][g] * ad;
#pragma unroll
            for (int off = 1; off < 16; off <<= 1) {
                vs += __shfl_xor(vs, off);
                vd += __shfl_xor(vd, off);
            }
            if (lm == 0) {
                red_s[w][r * 16 + quad * 4 + g] = vs;
                red_d[w][r * 16 + quad * 4 + g] = vd;
            }
        }
    }
    __syncthreads();
    if (t < 64) {
        float vs = red_s[0][t] + red_s[1][t] + red_s[2][t] + red_s[3][t];
        float vd = red_d[0][t] + red_d[1][t] + red_d[2][t] + red_d[3][t];
        int m = m0 + t;
        if (m < M) {
            asb[(size_t)m * Hstr + hd] = vs;
            adb[(size_t)m * Hstr + hd] = vd;
        }
    }
}

// ---------------------------------------------------------------------------
// Fused segment-softmax + aggregation, H=8, C=64 (layer 1), bf16 h.
// Single pass, no max subtraction (|e| <= ~2 analytically). Unrolled x4.
// ---------------------------------------------------------------------------
__global__ __launch_bounds__(256) void k_agg8(const unsigned short* __restrict__ h, // [N,512]
                                              const float* __restrict__ asrc,       // [N,8]
                                              const float* __restrict__ adst,       // [N,8]
                                              const int* __restrict__ rowptr,
                                              const int* __restrict__ col,
                                              const float* __restrict__ bias,       // [512]
                                              unsigned short* __restrict__ out) {   // [N,512]
    int n = blockIdx.x * 4 + (threadIdx.x >> 6);
    if (n >= N_NODES) return;
    int l = threadIdx.x & 63;
    int j = l >> 3;
    int start = rowptr[n], end = rowptr[n + 1];
    float adn = adst[n * 8 + j];

    float ssum = 0.f;
    float o[8] = {0.f, 0.f, 0.f, 0.f, 0.f, 0.f, 0.f, 0.f};
    int k = start;
    for (; k + 4 <= end; k += 4) {
        int s0 = col[k], s1 = col[k + 1], s2 = col[k + 2], s3 = col[k + 3];
        float t0 = asrc[s0 * 8 + j], t1 = asrc[s1 * 8 + j];
        float t2 = asrc[s2 * 8 + j], t3 = asrc[s3 * 8 + j];
        uint4 hv0 = *(const uint4*)(h + (size_t)s0 * 512 + l * 8);
        uint4 hv1 = *(const uint4*)(h + (size_t)s1 * 512 + l * 8);
        uint4 hv2 = *(const uint4*)(h + (size_t)s2 * 512 + l * 8);
        uint4 hv3 = *(const uint4*)(h + (size_t)s3 * 512 + l * 8);
        float f[8];
        float e0 = t0 + adn; e0 = (e0 > 0.f) ? e0 : 0.2f * e0;
        float ex0 = __expf(e0); ssum += ex0;
        unpack8(hv0, f);
#pragma unroll
        for (int i = 0; i < 8; ++i) o[i] += ex0 * f[i];
        float e1 = t1 + adn; e1 = (e1 > 0.f) ? e1 : 0.2f * e1;
        float ex1 = __expf(e1); ssum += ex1;
        unpack8(hv1, f);
#pragma unroll
        for (int i = 0; i < 8; ++i) o[i] += ex1 * f[i];
        float e2 = t2 + adn; e2 = (e2 > 0.f) ? e2 : 0.2f * e2;
        float ex2 = __expf(e2); ssum += ex2;
        unpack8(hv2, f);
#pragma unroll
        for (int i = 0; i < 8; ++i) o[i] += ex2 * f[i];
        float e3 = t3 + adn; e3 = (e3 > 0.f) ? e3 : 0.2f * e3;
        float ex3 = __expf(e3); ssum += ex3;
        unpack8(hv3, f);
#pragma unroll
        for (int i = 0; i < 8; ++i) o[i] += ex3 * f[i];
    }
    for (; k < end; ++k) {
        int s = col[k];
        float e = asrc[s * 8 + j] + adn;
        e = (e > 0.f) ? e : 0.2f * e;
        float ex = __expf(e);
        ssum += ex;
        uint4 hv = *(const uint4*)(h + (size_t)s * 512 + l * 8);
        float f[8];
        unpack8(hv, f);
#pragma unroll
        for (int i = 0; i < 8; ++i) o[i] += ex * f[i];
    }
    float inv = 1.f / (ssum + 1e-16f);
    unsigned int p[4];
#pragma unroll
    for (int i = 0; i < 4; ++i) {
        float v0 = o[2 * i] * inv + bias[l * 8 + 2 * i];
        float v1 = o[2 * i + 1] * inv + bias[l * 8 + 2 * i + 1];
        v0 = (v0 > 0.f) ? v0 : expm1f(v0);
        v1 = (v1 > 0.f) ? v1 : expm1f(v1);
        p[i] = (unsigned int)f2b(v0) | ((unsigned int)f2b(v1) << 16);
    }
    *(uint4*)(out + (size_t)n * 512 + l * 8) = make_uint4(p[0], p[1], p[2], p[3]);
}

// ---------------------------------------------------------------------------
// Fused segment-softmax + aggregation, H=1, C=64 (layers 2,3), bf16 h.
// Single pass, no max subtraction. Unrolled x4. Writes bf16 features.
// ---------------------------------------------------------------------------
__global__ __launch_bounds__(256) void k_agg1(const unsigned short* __restrict__ h, // [N,64]
                                              const float* __restrict__ asrc,       // [N]
                                              const float* __restrict__ adst,       // [N]
                                              const int* __restrict__ rowptr,
                                              const int* __restrict__ col,
                                              const float* __restrict__ bias,       // [64]
                                              unsigned short* __restrict__ out) {   // [N,64]
    int n = blockIdx.x * 4 + (threadIdx.x >> 6);
    if (n >= N_NODES) return;
    int l = threadIdx.x & 63;
    int start = rowptr[n], end = rowptr[n + 1];
    float adn = adst[n];

    float ssum = 0.f, o = 0.f;
    int k = start;
    for (; k + 4 <= end; k += 4) {
        int s0 = col[k], s1 = col[k + 1], s2 = col[k + 2], s3 = col[k + 3];
        float t0 = asrc[s0], t1 = asrc[s1], t2 = asrc[s2], t3 = asrc[s3];
        unsigned short q0 = h[(size_t)s0 * 64 + l];
        unsigned short q1 = h[(size_t)s1 * 64 + l];
        unsigned short q2 = h[(size_t)s2 * 64 + l];
        unsigned short q3 = h[(size_t)s3 * 64 + l];
        float e0 = t0 + adn; e0 = (e0 > 0.f) ? e0 : 0.2f * e0;
        float ex0 = __expf(e0); ssum += ex0; o += ex0 * b2f(q0);
        float e1 = t1 + adn; e1 = (e1 > 0.f) ? e1 : 0.2f * e1;
        float ex1 = __expf(e1); ssum += ex1; o += ex1 * b2f(q1);
        float e2 = t2 + adn; e2 = (e2 > 0.f) ? e2 : 0.2f * e2;
        float ex2 = __expf(e2); ssum += ex2; o += ex2 * b2f(q2);
        float e3 = t3 + adn; e3 = (e3 > 0.f) ? e3 : 0.2f * e3;
        float ex3 = __expf(e3); ssum += ex3; o += ex3 * b2f(q3);
    }
    for (; k < end; ++k) {
        int s = col[k];
        float e = asrc[s] + adn;
        e = (e > 0.f) ? e : 0.2f * e;
        float ex = __expf(e);
        ssum += ex;
        o += ex * b2f(h[(size_t)s * 64 + l]);
    }
    float v = o / (ssum + 1e-16f) + bias[l];
    v = (v > 0.f) ? v : expm1f(v);   // ELU
    out[(size_t)n * 64 + l] = f2b(v);
}

// ---------------------------------------------------------------------------
// Classifier: out[N,10] = h[N,64](bf16) @ Wc[10,64]^T + bc, fp32 out.
// Separate kernel: cheaper than 60 shfl/lane fused into the aggregation.
// ---------------------------------------------------------------------------
__global__ __launch_bounds__(256) void k_classifier(const unsigned short* __restrict__ h,
                                                    const float* __restrict__ Wc,
                                                    const float* __restrict__ bc,
                                                    float* __restrict__ out) {
    __shared__ float sW[640];
    for (int i = threadIdx.x; i < 640; i += blockDim.x) sW[i] = Wc[i];
    __syncthreads();
    int idx = blockIdx.x * blockDim.x + threadIdx.x;
    if (idx >= N_NODES * 10) return;
    int n = idx / 10, d = idx - n * 10;
    const unsigned short* hr = h + (size_t)n * 64;
    const float* wr = sW + d * 64;
    float acc = 0.f;
#pragma unroll
    for (int c = 0; c < 64; ++c) acc += b2f(hr[c]) * wr[c];
    out[idx] = acc + bc[d];
}

// ---------------------------------------------------------------------------
extern "C" void kernel_launch(void* const* d_in, const int* in_sizes, int n_in,
                              void* d_out, int out_size, void* d_ws, size_t ws_size,
                              hipStream_t stream) {
    const float* x    = (const float*)d_in[0];
    const int*   eidx = (const int*)  d_in[1];
    const float* W1   = (const float*)d_in[2];
    const float* a1s  = (const float*)d_in[3];
    const float* a1d  = (const float*)d_in[4];
    const float* b1   = (const float*)d_in[5];
    const float* W2   = (const float*)d_in[6];
    const float* a2s  = (const float*)d_in[7];
    const float* a2d  = (const float*)d_in[8];
    const float* b2   = (const float*)d_in[9];
    const float* W3   = (const float*)d_in[10];
    const float* a3s  = (const float*)d_in[11];
    const float* a3d  = (const float*)d_in[12];
    const float* b3   = (const float*)d_in[13];
    const float* Wc   = (const float*)d_in[14];
    const float* bc   = (const float*)d_in[15];
    float* out = (float*)d_out;

    // Workspace layout: fp32 first (16B alignment), then bf16, then ints
    float* asbuf = (float*)d_ws;                              // N*8
    float* adbuf = asbuf + (size_t)N_NODES * 8;               // N*8
    unsigned short* h1  = (unsigned short*)(adbuf + (size_t)N_NODES * 8); // N*512
    unsigned short* x2  = h1  + (size_t)N_NODES * 512;        // N*512
    unsigned short* h2  = x2  + (size_t)N_NODES * 512;        // N*64
    unsigned short* x3  = h2  + (size_t)N_NODES * 64;         // N*64
    unsigned short* h3  = x3  + (size_t)N_NODES * 64;         // N*64
    unsigned short* x4  = h3  + (size_t)N_NODES * 64;         // N*64
    unsigned short* W1b = x4  + (size_t)N_NODES * 64;         // 512*128
    unsigned short* W2b = W1b + 512 * 128;                    // 64*512
    unsigned short* W3b = W2b + 64 * 512;                     // 64*64
    int* ibase  = (int*)(W3b + 64 * 64);
    int* deg    = ibase;                                      // N   (zeroed in k_prep)
    int* flag   = deg + N_NODES;                              // 1   (zeroed in k_prep)
    int* rowptr = flag + 1;                                   // N+1
    int* cursor = rowptr + N_NODES + 1;                       // N
    int* bsum   = cursor + N_NODES;                           // 256
    int* boff   = bsum + 256;                                 // 256
    int* col    = boff + 256;                                 // ETOT

    dim3 blk(256);
    const int SCAN_BLOCKS = (N_NODES + 255) / 256;   // 196

    // Prep (zero deg/flag + weight casts), then CSR build
    k_prep<<<SCAN_BLOCKS, blk, 0, stream>>>(W1, W2, W3, W1b, W2b, W3b, deg, flag);
    k_detect<<<32, blk, 0, stream>>>(eidx, flag);
    k_degree<<<(ETOT + 255) / 256, blk, 0, stream>>>(eidx, flag, deg);
    k_scan1<<<SCAN_BLOCKS, blk, 0, stream>>>(deg, rowptr, bsum);
    k_scan2<<<1, blk, 0, stream>>>(bsum, boff, rowptr, SCAN_BLOCKS);
    k_scan3<<<SCAN_BLOCKS, blk, 0, stream>>>(rowptr, boff, cursor);
    k_scatter<<<(ETOT + 255) / 256, blk, 0, stream>>>(eidx, flag, cursor, col);

    int mblocks = (N_NODES + 63) / 64;   // 782
    int nblocks = N_NODES / 4;           // 12500 (exact)

    // Layer 1: x[N,128] fp32 -> h1[N,512] (+ attn coefs); agg -> x2
    k_gemm<1><<<dim3(8, mblocks), blk, 0, stream>>>(x, (const unsigned short*)0, W1b, h1,
                                                    a1s, a1d, asbuf, adbuf,
                                                    N_NODES, 128, 512, 8);
    k_agg8<<<nblocks, blk, 0, stream>>>(h1, asbuf, adbuf, rowptr, col, b1, x2);

    // Layer 2: x2[N,512] -> h2[N,64] (+ attn coefs); agg -> x3
    k_gemm<0><<<dim3(1, mblocks), blk, 0, stream>>>((const float*)0, x2, W2b, h2,
                                                    a2s, a2d, asbuf, adbuf,
                                                    N_NODES, 512, 64, 1);
    k_agg1<<<nblocks, blk, 0, stream>>>(h2, asbuf, adbuf, rowptr, col, b2, x3);

    // Layer 3: x3[N,64] -> h3[N,64] (+ attn coefs); agg -> x4
    k_gemm<0><<<dim3(1, mblocks), blk, 0, stream>>>((const float*)0, x3, W3b, h3,
                                                    a3s, a3d, asbuf, adbuf,
                                                    N_NODES, 64, 64, 1);
    k_agg1<<<nblocks, blk, 0, stream>>>(h3, asbuf, adbuf, rowptr, col, b3, x4);

    // Classifier
    k_classifier<<<(N_NODES * 10 + 255) / 256, blk, 0, stream>>>(x4, Wc, bc, out);
}